// Round 4
// baseline (372.451 us; speedup 1.0000x reference)
//
#include <hip/hip_runtime.h>

#define D 128
#define PSHIFT 9                 // 512 nodes per partition
#define PCAP 17664               // partition slab cap (mean 16327, +10 sigma)
#define SDEPTH 48                // LDS staging depth per partition
#define NP_MAX 256               // max partitions (static LDS sizing)
#define NBF 768                  // bin blocks (3 blocks/CU, 12 waves/CU)
#define BCAP 2560                // per-bucket compact cap (mean 2048, 11 sigma)
#define NPH 8                    // gather src-phases (3.2MB h window < 4MB L2/XCD)

typedef __attribute__((ext_vector_type(8))) short short8;
typedef __attribute__((ext_vector_type(4))) float f32x4;

__device__ __forceinline__ unsigned short f2bf(float f) {
    union { float f; unsigned int u; } c; c.f = f;
    unsigned int b = c.u;
    unsigned int r = (b + 0x7FFFu + ((b >> 16) & 1u)) >> 16;  // RTN-even
    return (unsigned short)r;
}
__device__ __forceinline__ float bf2f(unsigned short s) {
    union { unsigned int u; float f; } c; c.u = ((unsigned int)s) << 16;
    return c.f;
}

// ---------------------------------------------------------------------------
// Kernel A: init per-partition cursors (64B-padded lines).
// ---------------------------------------------------------------------------
__global__ void k_init(int* __restrict__ gcur, int np) {
    int i = blockIdx.x * 256 + threadIdx.x;
    if (i < np) gcur[i << 4] = i * PCAP;
}

// ---------------------------------------------------------------------------
// Kernel 1: h = bf16(x @ W^T) via MFMA, bf16 hi/lo split => fp32-equivalent.
// 256 thr = 4 waves x 32 rows = 128 rows/block. bounds(256,2): VGPR budget
// 256 (the 512-thr/bounds(512,4) round-3 version capped VGPR at 128 =>
// suspected scratch spills). All 16 x-loads hoisted before compute.
// ---------------------------------------------------------------------------
__global__ __launch_bounds__(256, 2) void k_gemm_mfma(const float* __restrict__ x,
                                                      const float* __restrict__ W,
                                                      unsigned short* __restrict__ h,
                                                      int N) {
    __shared__ unsigned short Wh[D * D];   // 32 KB
    __shared__ unsigned short Wl[D * D];   // 32 KB

    const int t = threadIdx.x;

    // stage W -> LDS (hi/lo bf16), XOR-swizzled rows (gk ^= o&7)
    for (int i = t; i < (D * D / 8); i += 256) {
        const int o = i >> 4;
        const int gk = i & 15;
        const float* wp = W + o * D + gk * 8;
        float4 a0 = *(const float4*)wp;
        float4 a1 = *(const float4*)(wp + 4);
        float v[8] = {a0.x, a0.y, a0.z, a0.w, a1.x, a1.y, a1.z, a1.w};
        unsigned short hi[8], lo[8];
#pragma unroll
        for (int j = 0; j < 8; j++) {
            hi[j] = f2bf(v[j]);
            lo[j] = f2bf(v[j] - bf2f(hi[j]));
        }
        const int base = o * D + ((gk ^ (o & 7)) << 3);
        ushort4 h0 = {hi[0], hi[1], hi[2], hi[3]};
        ushort4 h1 = {hi[4], hi[5], hi[6], hi[7]};
        ushort4 l0 = {lo[0], lo[1], lo[2], lo[3]};
        ushort4 l1 = {lo[4], lo[5], lo[6], lo[7]};
        *(ushort4*)&Wh[base] = h0;
        *(ushort4*)&Wh[base + 4] = h1;
        *(ushort4*)&Wl[base] = l0;
        *(ushort4*)&Wl[base + 4] = l1;
    }
    __syncthreads();

    const int lane = t & 63;
    const int wv = t >> 6;      // 0..3
    const int lr = lane & 15;   // A-row / B-col within 16-tile
    const int lg = lane >> 4;   // k-group (8 elems each)
    const int rowbase = blockIdx.x * 128 + wv * 32;

    // hoist ALL x loads (16 float4 = 64 VGPR) -> one vmcnt drain, deep MLP
    float4 xr[2][4][2];   // [rg][ks][half]
#pragma unroll
    for (int rg = 0; rg < 2; rg++) {
        const int row = rowbase + rg * 16 + lr;
        const float* xp = x + (size_t)row * D + lg * 8;
        const bool ok = (row < N);
#pragma unroll
        for (int ks = 0; ks < 4; ks++) {
            xr[rg][ks][0] = ok ? *(const float4*)(xp + ks * 32) : make_float4(0.f, 0.f, 0.f, 0.f);
            xr[rg][ks][1] = ok ? *(const float4*)(xp + ks * 32 + 4) : make_float4(0.f, 0.f, 0.f, 0.f);
        }
    }

    f32x4 acc[2][8];
#pragma unroll
    for (int a = 0; a < 2; a++)
#pragma unroll
        for (int b = 0; b < 8; b++)
            acc[a][b] = (f32x4){0.f, 0.f, 0.f, 0.f};

#pragma unroll
    for (int ks = 0; ks < 4; ks++) {        // K steps of 32
        short8 ah[2], al[2];
#pragma unroll
        for (int rg = 0; rg < 2; rg++) {
            float v[8] = {xr[rg][ks][0].x, xr[rg][ks][0].y, xr[rg][ks][0].z, xr[rg][ks][0].w,
                          xr[rg][ks][1].x, xr[rg][ks][1].y, xr[rg][ks][1].z, xr[rg][ks][1].w};
#pragma unroll
            for (int j = 0; j < 8; j++) {
                unsigned short hj = f2bf(v[j]);
                ah[rg][j] = (short)hj;
                al[rg][j] = (short)f2bf(v[j] - bf2f(hj));
            }
        }
#pragma unroll
        for (int tt = 0; tt < 8; tt++) {    // 8 N-tiles of 16
            const int o = tt * 16 + lr;
            const int eoff = o * D + ((((ks << 2) + lg) ^ (lr & 7)) << 3);
            short8 bh = *(const short8*)&Wh[eoff];
            short8 bl = *(const short8*)&Wl[eoff];
#pragma unroll
            for (int rg = 0; rg < 2; rg++) {
                acc[rg][tt] = __builtin_amdgcn_mfma_f32_16x16x32_bf16(ah[rg], bh, acc[rg][tt], 0, 0, 0);
                acc[rg][tt] = __builtin_amdgcn_mfma_f32_16x16x32_bf16(al[rg], bh, acc[rg][tt], 0, 0, 0);
                acc[rg][tt] = __builtin_amdgcn_mfma_f32_16x16x32_bf16(ah[rg], bl, acc[rg][tt], 0, 0, 0);
            }
        }
    }

    // C/D layout (m89-verified): col = lane&15, row = (lane>>4)*4 + i
#pragma unroll
    for (int rg = 0; rg < 2; rg++) {
#pragma unroll
        for (int i = 0; i < 4; i++) {
            const int row = rowbase + rg * 16 + lg * 4 + i;
            if (row < N) {
                unsigned short* hp = h + (size_t)row * D + lr;
#pragma unroll
                for (int tt = 0; tt < 8; tt++)
                    hp[tt * 16] = f2bf(acc[rg][tt][i]);
            }
        }
    }
}

// ---------------------------------------------------------------------------
// Kernel 2: coarse bin into 196 partitions with LDS-staged, LINE-LOCAL
// flushes. Place pass: LDS atomic slot in partition's staging (depth 48;
// astronomically-rare overflow goes direct). Flush: ONE thread per partition
// reserves an exact run (one global atomic on a padded cursor) and copies
// the batch => same-line store bursts. Kills round-3's 3.2M scattered-line
// stores (122MB write-back for a 12.8MB payload).
// entry = src | (dst & 511) << 17  (26 bits).
// ---------------------------------------------------------------------------
__global__ __launch_bounds__(256) void k_bin1(const int* __restrict__ src,
                                              const int* __restrict__ dst,
                                              int* __restrict__ gcur,
                                              unsigned* __restrict__ packed,
                                              int E, int np, int epb) {
    __shared__ unsigned stage[NP_MAX * SDEPTH];  // 49 KB
    __shared__ int scnt[NP_MAX];

    const int t = threadIdx.x;
    for (int i = t; i < np; i += 256) scnt[i] = 0;
    __syncthreads();

    const int beg = blockIdx.x * epb;
    const int end = min(beg + epb, E);
    for (int e = beg + t; e < end; e += 256) {
        const int d = dst[e];
        const int s = src[e];
        const int p = d >> PSHIFT;
        const unsigned entry = (unsigned)s | ((unsigned)(d & ((1 << PSHIFT) - 1)) << 17);
        const int slot = atomicAdd(&scnt[p], 1);
        if (slot < SDEPTH) {
            stage[p * SDEPTH + slot] = entry;
        } else {  // rare overflow: direct exact reservation
            const int pos = atomicAdd(&gcur[p << 4], 1);
            if (pos - p * PCAP < PCAP) packed[pos] = entry;
        }
    }
    __syncthreads();

    for (int i = t; i < np; i += 256) {
        const int c = min(scnt[i], SDEPTH);
        if (c) {
            const int base = atomicAdd(&gcur[i << 4], c);
            const int lim = (i + 1) * PCAP;
            for (int j = 0; j < c; j++) {
                const int pos = base + j;
                if (pos < lim) packed[pos] = stage[i * SDEPTH + j];
            }
        }
    }
}

// ---------------------------------------------------------------------------
// Kernel 3: one block per 64-node bucket. Scans its partition's slab
// (coalesced, L2/L3-resident), compacts its 1/8 into LDS, counting-sorts
// with key = (local&63)<<3 | src>>14  => 8 src-phases; each phase's h
// window is 3.2MB (< 4MB per-XCD L2) for L2-blocked random gathers.
// ---------------------------------------------------------------------------
__global__ __launch_bounds__(256) void k_gather(const unsigned short* __restrict__ h,
                                                const unsigned* __restrict__ packed,
                                                const int* __restrict__ gcur,
                                                float* __restrict__ out, int N) {
    __shared__ unsigned tmp[BCAP];    // 10 KB
    __shared__ unsigned lsrc[BCAP];   // 10 KB
    __shared__ int cnt[512];
    __shared__ int off2[513];
    __shared__ int curs[512];
    __shared__ int part[256];
    __shared__ int nmine_s;

    const int bk = blockIdx.x;       // bucket of 64 nodes
    const int p = bk >> 3;
    const int sub = bk & 7;
    const int t = threadIdx.x;
    const int hw = t >> 5;           // half-wave 0..7
    const int f = (t & 31) << 2;     // feature offset

    const int base = p * PCAP;
    const int sz = min(gcur[p << 4] - base, PCAP);
    const unsigned* pk = packed + (size_t)base;

    if (t == 0) nmine_s = 0;
    cnt[t] = 0; cnt[t + 256] = 0;
    __syncthreads();

    // compact this bucket's entries (local>>6 == sub; bits 23..25)
    for (int i = t; i < sz; i += 256) {
        const unsigned e = pk[i];
        if ((int)(e >> 23) == sub) {
            const int pos = atomicAdd(&nmine_s, 1);
            if (pos < BCAP) tmp[pos] = e & 0x7FFFFFu;   // (local&63)<<17 | src
        }
    }
    __syncthreads();
    const int m = min(nmine_s, BCAP);

    // count 512 keys: key = bits 14..22 = (local&63)<<3 | (src>>14)
    for (int i = t; i < m; i += 256) atomicAdd(&cnt[(tmp[i] >> 14) & 511u], 1);
    __syncthreads();

    // two-level exclusive scan of 512 counters
    part[t] = cnt[2 * t] + cnt[2 * t + 1];
    __syncthreads();
    if (t == 0) {
        int s = 0;
        for (int j = 0; j < 256; j++) { const int v = part[j]; part[j] = s; s += v; }
        off2[512] = s;
    }
    __syncthreads();
    off2[2 * t] = part[t];
    off2[2 * t + 1] = part[t] + cnt[2 * t];
    __syncthreads();
    curs[2 * t] = off2[2 * t];
    curs[2 * t + 1] = off2[2 * t + 1];
    __syncthreads();

    for (int i = t; i < m; i += 256) {
        const unsigned e = tmp[i];
        const int pos = atomicAdd(&curs[(e >> 14) & 511u], 1);
        lsrc[pos] = e & 0x1FFFFu;
    }
    __syncthreads();

    float4 acc[8];
#pragma unroll
    for (int r = 0; r < 8; r++) acc[r] = make_float4(0.f, 0.f, 0.f, 0.f);

    for (int q = 0; q < NPH; q++) {       // src-phase (L2 window ~3.2MB)
#pragma unroll
        for (int r = 0; r < 8; r++) {
            const int nl = hw + (r << 3);
            const int idx = (nl << 3) + q;
            int j = off2[idx];
            const int je = off2[idx + 1];
            float4 a = acc[r];
            for (; j + 3 < je; j += 4) {
                int s0 = lsrc[j], s1 = lsrc[j + 1], s2 = lsrc[j + 2], s3 = lsrc[j + 3];
                ushort4 v0 = *(const ushort4*)(h + (size_t)s0 * D + f);
                ushort4 v1 = *(const ushort4*)(h + (size_t)s1 * D + f);
                ushort4 v2 = *(const ushort4*)(h + (size_t)s2 * D + f);
                ushort4 v3 = *(const ushort4*)(h + (size_t)s3 * D + f);
                a.x += bf2f(v0.x) + bf2f(v1.x) + bf2f(v2.x) + bf2f(v3.x);
                a.y += bf2f(v0.y) + bf2f(v1.y) + bf2f(v2.y) + bf2f(v3.y);
                a.z += bf2f(v0.z) + bf2f(v1.z) + bf2f(v2.z) + bf2f(v3.z);
                a.w += bf2f(v0.w) + bf2f(v1.w) + bf2f(v2.w) + bf2f(v3.w);
            }
            for (; j < je; j++) {
                int s0 = lsrc[j];
                ushort4 v0 = *(const ushort4*)(h + (size_t)s0 * D + f);
                a.x += bf2f(v0.x); a.y += bf2f(v0.y);
                a.z += bf2f(v0.z); a.w += bf2f(v0.w);
            }
            acc[r] = a;
        }
    }

#pragma unroll
    for (int r = 0; r < 8; r++) {
        const int node = (bk << 6) + hw + (r << 3);
        if (node < N) *(float4*)(out + (size_t)node * D + f) = acc[r];
    }
}

extern "C" void kernel_launch(void* const* d_in, const int* in_sizes, int n_in,
                              void* d_out, int out_size, void* d_ws, size_t ws_size,
                              hipStream_t stream) {
    const float* x = (const float*)d_in[0];   // [N, 128]
    const float* W = (const float*)d_in[1];   // [128, 128]
    const int* ei  = (const int*)d_in[2];     // [2, E] flat
    float* out = (float*)d_out;               // [N, 128]

    const int N = in_sizes[0] / D;            // 100000
    const int E = in_sizes[2] / 2;            // 3200000
    const int np = (N + 511) >> PSHIFT;       // 196 partitions
    const int nb = (N + 63) >> 6;             // 1563 buckets
    const int epb = (E + NBF - 1) / NBF;      // 4167 edges per bin block

    const int* srcp = ei;
    const int* dstp = ei + E;

    // workspace layout (16B-aligned slabs)
    char* ws = (char*)d_ws;
    unsigned short* h = (unsigned short*)ws;
                                      ws += (size_t)N * D * 2;                // 25.6 MB
    unsigned* packed = (unsigned*)ws; ws += (size_t)np * PCAP * 4;            // 13.9 MB
    int* gcur = (int*)ws;             ws += (size_t)np * 64;                  // 12.5 KB (64B-padded)

    k_init<<<(np + 255) / 256, 256, 0, stream>>>(gcur, np);
    k_gemm_mfma<<<(N + 127) / 128, 256, 0, stream>>>(x, W, h, N);
    k_bin1<<<NBF, 256, 0, stream>>>(srcp, dstp, gcur, packed, E, np, epb);
    k_gather<<<nb, 256, 0, stream>>>(h, packed, gcur, out, N);
}

// Round 5
// 279.955 us; speedup vs baseline: 1.3304x; 1.3304x over previous
//
#include <hip/hip_runtime.h>

#define D 128
#define PSHIFT 9                 // 512 nodes per partition
#define PCAP 17664               // partition slab cap (mean 16327, sigma~128, +10s)
#define SDEPTH 48                // bin1 LDS staging depth per partition
#define NP_MAX 256               // max partitions (static LDS sizing)
#define NBF 768                  // bin1 blocks (3 blocks/CU)
#define BCAP 2560                // per-bucket slab cap (mean 2048, sigma~45)
#define CHUNK 2048               // bin2 chunk size

typedef __attribute__((ext_vector_type(8))) short short8;
typedef __attribute__((ext_vector_type(4))) float f32x4;

__device__ __forceinline__ unsigned short f2bf(float f) {
    union { float f; unsigned int u; } c; c.f = f;
    unsigned int b = c.u;
    unsigned int r = (b + 0x7FFFu + ((b >> 16) & 1u)) >> 16;  // RTN-even
    return (unsigned short)r;
}
__device__ __forceinline__ float bf2f(unsigned short s) {
    union { unsigned int u; float f; } c; c.u = ((unsigned int)s) << 16;
    return c.f;
}

// ---------------------------------------------------------------------------
// Kernel A: init partition cursors + bucket cursors (64B-padded lines).
// ---------------------------------------------------------------------------
__global__ void k_init(int* __restrict__ gcur, int np, int* __restrict__ bcur, int nb) {
    int i = blockIdx.x * 256 + threadIdx.x;
    if (i < np) gcur[i << 4] = i * PCAP;
    if (i < nb) bcur[i << 4] = i * BCAP;
}

// ---------------------------------------------------------------------------
// Kernel 1: h = bf16(x @ W^T) via MFMA, bf16 hi/lo split => fp32-equivalent.
// (unchanged control from round 4)
// ---------------------------------------------------------------------------
__global__ __launch_bounds__(256, 2) void k_gemm_mfma(const float* __restrict__ x,
                                                      const float* __restrict__ W,
                                                      unsigned short* __restrict__ h,
                                                      int N) {
    __shared__ unsigned short Wh[D * D];   // 32 KB
    __shared__ unsigned short Wl[D * D];   // 32 KB

    const int t = threadIdx.x;

    for (int i = t; i < (D * D / 8); i += 256) {
        const int o = i >> 4;
        const int gk = i & 15;
        const float* wp = W + o * D + gk * 8;
        float4 a0 = *(const float4*)wp;
        float4 a1 = *(const float4*)(wp + 4);
        float v[8] = {a0.x, a0.y, a0.z, a0.w, a1.x, a1.y, a1.z, a1.w};
        unsigned short hi[8], lo[8];
#pragma unroll
        for (int j = 0; j < 8; j++) {
            hi[j] = f2bf(v[j]);
            lo[j] = f2bf(v[j] - bf2f(hi[j]));
        }
        const int base = o * D + ((gk ^ (o & 7)) << 3);
        ushort4 h0 = {hi[0], hi[1], hi[2], hi[3]};
        ushort4 h1 = {hi[4], hi[5], hi[6], hi[7]};
        ushort4 l0 = {lo[0], lo[1], lo[2], lo[3]};
        ushort4 l1 = {lo[4], lo[5], lo[6], lo[7]};
        *(ushort4*)&Wh[base] = h0;
        *(ushort4*)&Wh[base + 4] = h1;
        *(ushort4*)&Wl[base] = l0;
        *(ushort4*)&Wl[base + 4] = l1;
    }
    __syncthreads();

    const int lane = t & 63;
    const int wv = t >> 6;      // 0..3
    const int lr = lane & 15;
    const int lg = lane >> 4;
    const int rowbase = blockIdx.x * 128 + wv * 32;

    float4 xr[2][4][2];   // hoisted x loads
#pragma unroll
    for (int rg = 0; rg < 2; rg++) {
        const int row = rowbase + rg * 16 + lr;
        const float* xp = x + (size_t)row * D + lg * 8;
        const bool ok = (row < N);
#pragma unroll
        for (int ks = 0; ks < 4; ks++) {
            xr[rg][ks][0] = ok ? *(const float4*)(xp + ks * 32) : make_float4(0.f, 0.f, 0.f, 0.f);
            xr[rg][ks][1] = ok ? *(const float4*)(xp + ks * 32 + 4) : make_float4(0.f, 0.f, 0.f, 0.f);
        }
    }

    f32x4 acc[2][8];
#pragma unroll
    for (int a = 0; a < 2; a++)
#pragma unroll
        for (int b = 0; b < 8; b++)
            acc[a][b] = (f32x4){0.f, 0.f, 0.f, 0.f};

#pragma unroll
    for (int ks = 0; ks < 4; ks++) {
        short8 ah[2], al[2];
#pragma unroll
        for (int rg = 0; rg < 2; rg++) {
            float v[8] = {xr[rg][ks][0].x, xr[rg][ks][0].y, xr[rg][ks][0].z, xr[rg][ks][0].w,
                          xr[rg][ks][1].x, xr[rg][ks][1].y, xr[rg][ks][1].z, xr[rg][ks][1].w};
#pragma unroll
            for (int j = 0; j < 8; j++) {
                unsigned short hj = f2bf(v[j]);
                ah[rg][j] = (short)hj;
                al[rg][j] = (short)f2bf(v[j] - bf2f(hj));
            }
        }
#pragma unroll
        for (int tt = 0; tt < 8; tt++) {
            const int o = tt * 16 + lr;
            const int eoff = o * D + ((((ks << 2) + lg) ^ (lr & 7)) << 3);
            short8 bh = *(const short8*)&Wh[eoff];
            short8 bl = *(const short8*)&Wl[eoff];
#pragma unroll
            for (int rg = 0; rg < 2; rg++) {
                acc[rg][tt] = __builtin_amdgcn_mfma_f32_16x16x32_bf16(ah[rg], bh, acc[rg][tt], 0, 0, 0);
                acc[rg][tt] = __builtin_amdgcn_mfma_f32_16x16x32_bf16(al[rg], bh, acc[rg][tt], 0, 0, 0);
                acc[rg][tt] = __builtin_amdgcn_mfma_f32_16x16x32_bf16(ah[rg], bl, acc[rg][tt], 0, 0, 0);
            }
        }
    }

#pragma unroll
    for (int rg = 0; rg < 2; rg++) {
#pragma unroll
        for (int i = 0; i < 4; i++) {
            const int row = rowbase + rg * 16 + lg * 4 + i;
            if (row < N) {
                unsigned short* hp = h + (size_t)row * D + lr;
#pragma unroll
                for (int tt = 0; tt < 8; tt++)
                    hp[tt * 16] = f2bf(acc[rg][tt][i]);
            }
        }
    }
}

// ---------------------------------------------------------------------------
// Kernel 2: coarse bin into 196 partitions, LDS-staged LINE-LOCAL flushes.
// (round-4 k_bin1, kept: not in top-5 => reasonably fast)
// entry = src | (dst & 511) << 17.
// ---------------------------------------------------------------------------
__global__ __launch_bounds__(256) void k_bin1(const int* __restrict__ src,
                                              const int* __restrict__ dst,
                                              int* __restrict__ gcur,
                                              unsigned* __restrict__ packed,
                                              int E, int np, int epb) {
    __shared__ unsigned stage[NP_MAX * SDEPTH];  // 49 KB
    __shared__ int scnt[NP_MAX];

    const int t = threadIdx.x;
    for (int i = t; i < np; i += 256) scnt[i] = 0;
    __syncthreads();

    const int beg = blockIdx.x * epb;
    const int end = min(beg + epb, E);
    for (int e = beg + t; e < end; e += 256) {
        const int d = dst[e];
        const int s = src[e];
        const int p = d >> PSHIFT;
        const unsigned entry = (unsigned)s | ((unsigned)(d & ((1 << PSHIFT) - 1)) << 17);
        const int slot = atomicAdd(&scnt[p], 1);
        if (slot < SDEPTH) {
            stage[p * SDEPTH + slot] = entry;
        } else {
            const int pos = atomicAdd(&gcur[p << 4], 1);
            if (pos - p * PCAP < PCAP) packed[pos] = entry;
        }
    }
    __syncthreads();

    for (int i = t; i < np; i += 256) {
        const int c = min(scnt[i], SDEPTH);
        if (c) {
            const int base = atomicAdd(&gcur[i << 4], c);
            const int lim = (i + 1) * PCAP;
            for (int j = 0; j < c; j++) {
                const int pos = base + j;
                if (pos < lim) packed[pos] = stage[i * SDEPTH + j];
            }
        }
    }
}

// ---------------------------------------------------------------------------
// Kernel 3 (NEW): split each partition slab into its 8 bucket slabs.
// 4 blocks/partition, chunked LDS counting-sort with 8 keys (e>>23):
// coalesced slab reads, per-bin ~1KB burst writes at exactly-reserved
// cursors (one global atomic per bin per chunk). Replaces round-4's
// 8x-redundant in-gather compaction. Output entry = e & 0x7FFFFF
// (= src | (dst&63)<<17, what gather expects).
// ---------------------------------------------------------------------------
__global__ __launch_bounds__(256) void k_bin2(const unsigned* __restrict__ packed,
                                              const int* __restrict__ gcur,
                                              int* __restrict__ bcur,
                                              unsigned* __restrict__ bslab,
                                              int np) {
    __shared__ unsigned raw[CHUNK];   // 8 KB
    __shared__ unsigned srt[CHUNK];   // 8 KB
    __shared__ int c8[8], o8[9], cur8[8], gbase[8];

    const int p = blockIdx.x >> 2;
    const int qb = blockIdx.x & 3;
    const int t = threadIdx.x;

    const int base = p * PCAP;
    const int sz = min(gcur[p << 4] - base, PCAP);
    const int per = (sz + 3) >> 2;
    const int rbeg = qb * per;
    const int rend = min(rbeg + per, sz);
    const unsigned* pk = packed + (size_t)base;

    for (int cbeg = rbeg; cbeg < rend; cbeg += CHUNK) {
        const int n = min(CHUNK, rend - cbeg);
        for (int i = t; i < n; i += 256) raw[i] = pk[cbeg + i];
        if (t < 8) c8[t] = 0;
        __syncthreads();
        for (int i = t; i < n; i += 256) atomicAdd(&c8[raw[i] >> 23], 1);
        __syncthreads();
        if (t == 0) {
            int s = 0;
#pragma unroll
            for (int j = 0; j < 8; j++) { o8[j] = s; s += c8[j]; }
            o8[8] = s;
        }
        __syncthreads();
        if (t < 8) {
            cur8[t] = o8[t];
            gbase[t] = atomicAdd(&bcur[(p * 8 + t) << 4], c8[t]);
        }
        __syncthreads();
        for (int i = t; i < n; i += 256) {
            const unsigned e = raw[i];
            const int pos = atomicAdd(&cur8[e >> 23], 1);
            srt[pos] = e & 0x7FFFFFu;
        }
        __syncthreads();
#pragma unroll
        for (int b = 0; b < 8; b++) {
            const int cnt = o8[b + 1] - o8[b];
            const int gb = gbase[b];
            const int lim = (p * 8 + b + 1) * BCAP;
            const int m2 = min(cnt, max(0, lim - gb));
            for (int i = t; i < m2; i += 256) bslab[gb + i] = srt[o8[b] + i];
        }
        __syncthreads();
    }
}

// ---------------------------------------------------------------------------
// Kernel 4: gather — REVERTED to round-3 version (measured <=110 us).
// One block per 64-node bucket; 256-key LDS counting-sort
// (key = (local&63)<<2 | src-quadrant); 4 src-phases (~8MB h window).
// ---------------------------------------------------------------------------
__global__ __launch_bounds__(256) void k_gather(const unsigned short* __restrict__ h,
                                                const unsigned* __restrict__ bslab,
                                                const int* __restrict__ bcur,
                                                float* __restrict__ out, int N) {
    __shared__ unsigned lsrc[BCAP];   // 10 KB
    __shared__ int cnt[256];
    __shared__ int off[257];
    __shared__ int curs[256];

    const int bk = blockIdx.x;
    const int t = threadIdx.x;
    const int hw = t >> 5;
    const int f = (t & 31) << 2;

    const int sz = min(bcur[bk << 4] - bk * BCAP, BCAP);
    const unsigned* pk = bslab + (size_t)bk * BCAP;

    cnt[t] = 0;
    __syncthreads();
    for (int i = t; i < sz; i += 256)
        atomicAdd(&cnt[(pk[i] >> 15) & 255u], 1);
    __syncthreads();
    if (t == 0) {
        int s = 0;
        for (int j = 0; j < 256; j++) { off[j] = s; s += cnt[j]; }
        off[256] = s;
    }
    __syncthreads();
    curs[t] = off[t];
    __syncthreads();
    for (int i = t; i < sz; i += 256) {
        unsigned p = pk[i];
        int pos = atomicAdd(&curs[(p >> 15) & 255u], 1);
        lsrc[pos] = p & 0x1FFFFu;
    }
    __syncthreads();

    float4 acc[8];
#pragma unroll
    for (int r = 0; r < 8; r++) acc[r] = make_float4(0.f, 0.f, 0.f, 0.f);

    for (int q = 0; q < 4; q++) {
#pragma unroll
        for (int r = 0; r < 8; r++) {
            const int nl = hw + (r << 3);
            const int idx = (nl << 2) + q;
            int j = off[idx];
            const int je = off[idx + 1];
            float4 a = acc[r];
            for (; j + 3 < je; j += 4) {
                int s0 = lsrc[j], s1 = lsrc[j + 1], s2 = lsrc[j + 2], s3 = lsrc[j + 3];
                ushort4 v0 = *(const ushort4*)(h + (size_t)s0 * D + f);
                ushort4 v1 = *(const ushort4*)(h + (size_t)s1 * D + f);
                ushort4 v2 = *(const ushort4*)(h + (size_t)s2 * D + f);
                ushort4 v3 = *(const ushort4*)(h + (size_t)s3 * D + f);
                a.x += bf2f(v0.x) + bf2f(v1.x) + bf2f(v2.x) + bf2f(v3.x);
                a.y += bf2f(v0.y) + bf2f(v1.y) + bf2f(v2.y) + bf2f(v3.y);
                a.z += bf2f(v0.z) + bf2f(v1.z) + bf2f(v2.z) + bf2f(v3.z);
                a.w += bf2f(v0.w) + bf2f(v1.w) + bf2f(v2.w) + bf2f(v3.w);
            }
            for (; j < je; j++) {
                int s0 = lsrc[j];
                ushort4 v0 = *(const ushort4*)(h + (size_t)s0 * D + f);
                a.x += bf2f(v0.x); a.y += bf2f(v0.y);
                a.z += bf2f(v0.z); a.w += bf2f(v0.w);
            }
            acc[r] = a;
        }
    }

#pragma unroll
    for (int r = 0; r < 8; r++) {
        int node = (bk << 6) + hw + (r << 3);
        if (node < N) *(float4*)(out + (size_t)node * D + f) = acc[r];
    }
}

extern "C" void kernel_launch(void* const* d_in, const int* in_sizes, int n_in,
                              void* d_out, int out_size, void* d_ws, size_t ws_size,
                              hipStream_t stream) {
    const float* x = (const float*)d_in[0];   // [N, 128]
    const float* W = (const float*)d_in[1];   // [128, 128]
    const int* ei  = (const int*)d_in[2];     // [2, E] flat
    float* out = (float*)d_out;               // [N, 128]

    const int N = in_sizes[0] / D;            // 100000
    const int E = in_sizes[2] / 2;            // 3200000
    const int np = (N + 511) >> PSHIFT;       // 196 partitions
    const int nb = (N + 63) >> 6;             // 1563 buckets
    const int epb = (E + NBF - 1) / NBF;      // 4167 edges per bin1 block

    const int* srcp = ei;
    const int* dstp = ei + E;

    // workspace layout (16B-aligned slabs)
    char* ws = (char*)d_ws;
    unsigned short* h = (unsigned short*)ws;
                                      ws += (size_t)N * D * 2;                // 25.6 MB
    unsigned* packed = (unsigned*)ws; ws += (size_t)np * PCAP * 4;            // 13.9 MB
    unsigned* bslab = (unsigned*)ws;  ws += (size_t)nb * BCAP * 4;            // 16.0 MB
    int* gcur = (int*)ws;             ws += (size_t)np * 64;                  // 12.5 KB
    int* bcur = (int*)ws;             ws += (size_t)nb * 64;                  // 100 KB

    k_init<<<(nb + 255) / 256, 256, 0, stream>>>(gcur, np, bcur, nb);
    k_gemm_mfma<<<(N + 127) / 128, 256, 0, stream>>>(x, W, h, N);
    k_bin1<<<NBF, 256, 0, stream>>>(srcp, dstp, gcur, packed, E, np, epb);
    k_bin2<<<np * 4, 256, 0, stream>>>(packed, gcur, bcur, bslab, np);
    k_gather<<<nb, 256, 0, stream>>>(h, bslab, bcur, out, N);
}

// Round 6
// 273.123 us; speedup vs baseline: 1.3637x; 1.0250x over previous
//
#include <hip/hip_runtime.h>

#define D 128
#define PSHIFT 9                 // 512 nodes per partition
#define PCAP 17664               // partition slab cap (mean 16327, sigma~128, +10s)
#define SDEPTH 48                // bin1 LDS staging depth per partition
#define NP_MAX 256               // max partitions (static LDS sizing)
#define NBF 768                  // bin1 blocks (3 blocks/CU)
#define BCAP 2560                // per-bucket slab cap (mean 2048, sigma~45)
#define CHUNK 2048               // bin2 chunk size
#define OW 136                   // writeout LDS row stride (ushorts; 272B, 16B-aligned rows)

typedef __attribute__((ext_vector_type(8))) short short8;
typedef __attribute__((ext_vector_type(4))) float f32x4;

__device__ __forceinline__ unsigned short f2bf(float f) {
    union { float f; unsigned int u; } c; c.f = f;
    unsigned int b = c.u;
    unsigned int r = (b + 0x7FFFu + ((b >> 16) & 1u)) >> 16;  // RTN-even
    return (unsigned short)r;
}
__device__ __forceinline__ float bf2f(unsigned short s) {
    union { unsigned int u; float f; } c; c.u = ((unsigned int)s) << 16;
    return c.f;
}

// ---------------------------------------------------------------------------
// Kernel A: init partition cursors + bucket cursors (64B-padded lines).
// ---------------------------------------------------------------------------
__global__ void k_init(int* __restrict__ gcur, int np, int* __restrict__ bcur, int nb) {
    int i = blockIdx.x * 256 + threadIdx.x;
    if (i < np) gcur[i << 4] = i * PCAP;
    if (i < nb) bcur[i << 4] = i * BCAP;
}

// ---------------------------------------------------------------------------
// Kernel P (NEW): W -> swizzled hi/lo bf16, ONCE to global (64 KB).
// Removes per-gemm-block conversion VALU + lets gemm stage via pure copies.
// Layout matches gemm's B-fragment reads: base = o*D + ((gk ^ (o&7))<<3),
// Wh in [0,16384), Wl in [16384,32768).
// ---------------------------------------------------------------------------
__global__ __launch_bounds__(256) void k_prep(const float* __restrict__ W,
                                              unsigned short* __restrict__ whl) {
    const int i = blockIdx.x * 256 + threadIdx.x;   // 2048 groups of 8 elems
    if (i >= (D * D / 8)) return;
    const int o = i >> 4;
    const int gk = i & 15;
    const float* wp = W + o * D + gk * 8;
    float4 a0 = *(const float4*)wp;
    float4 a1 = *(const float4*)(wp + 4);
    float v[8] = {a0.x, a0.y, a0.z, a0.w, a1.x, a1.y, a1.z, a1.w};
    unsigned short hi[8], lo[8];
#pragma unroll
    for (int j = 0; j < 8; j++) {
        hi[j] = f2bf(v[j]);
        lo[j] = f2bf(v[j] - bf2f(hi[j]));
    }
    const int base = o * D + ((gk ^ (o & 7)) << 3);
    ushort4 h0 = {hi[0], hi[1], hi[2], hi[3]};
    ushort4 h1 = {hi[4], hi[5], hi[6], hi[7]};
    ushort4 l0 = {lo[0], lo[1], lo[2], lo[3]};
    ushort4 l1 = {lo[4], lo[5], lo[6], lo[7]};
    *(ushort4*)&whl[base] = h0;
    *(ushort4*)&whl[base + 4] = h1;
    *(ushort4*)&whl[16384 + base] = l0;
    *(ushort4*)&whl[16384 + base + 4] = l1;
}

// ---------------------------------------------------------------------------
// Kernel 1: h = bf16(x @ W^T) via MFMA, bf16 hi/lo split => fp32-equivalent.
// Changes vs round 5: (a) stage pre-converted WhWl with pure 16B copies;
// (b) C-writeout via LDS re-use (barrier-protected) + coalesced short8
// stores — replaces 64 scattered 2B global stores/thread (suspected 6x
// slowdown: sub-dword scatter is the TA slow path). MFMA core unchanged.
// ---------------------------------------------------------------------------
__global__ __launch_bounds__(256, 2) void k_gemm_mfma(const float* __restrict__ x,
                                                      const unsigned short* __restrict__ whl,
                                                      unsigned short* __restrict__ h,
                                                      int N) {
    __shared__ unsigned short sbuf[2 * 16384];   // 64 KB: WhWl; later writeout tile

    const int t = threadIdx.x;

    // stage pre-converted WhWl -> LDS (pure float4 copies, 16 iters)
    {
        const float4* g4 = (const float4*)whl;
        float4* l4 = (float4*)sbuf;
#pragma unroll
        for (int i = 0; i < 16; i++) l4[t + i * 256] = g4[t + i * 256];
    }
    __syncthreads();

    const int lane = t & 63;
    const int wv = t >> 6;      // 0..3
    const int lr = lane & 15;
    const int lg = lane >> 4;
    const int rowbase = blockIdx.x * 128 + wv * 32;

    float4 xr[2][4][2];   // hoisted x loads
#pragma unroll
    for (int rg = 0; rg < 2; rg++) {
        const int row = rowbase + rg * 16 + lr;
        const float* xp = x + (size_t)row * D + lg * 8;
        const bool ok = (row < N);
#pragma unroll
        for (int ks = 0; ks < 4; ks++) {
            xr[rg][ks][0] = ok ? *(const float4*)(xp + ks * 32) : make_float4(0.f, 0.f, 0.f, 0.f);
            xr[rg][ks][1] = ok ? *(const float4*)(xp + ks * 32 + 4) : make_float4(0.f, 0.f, 0.f, 0.f);
        }
    }

    f32x4 acc[2][8];
#pragma unroll
    for (int a = 0; a < 2; a++)
#pragma unroll
        for (int b = 0; b < 8; b++)
            acc[a][b] = (f32x4){0.f, 0.f, 0.f, 0.f};

#pragma unroll
    for (int ks = 0; ks < 4; ks++) {
        short8 ah[2], al[2];
#pragma unroll
        for (int rg = 0; rg < 2; rg++) {
            float v[8] = {xr[rg][ks][0].x, xr[rg][ks][0].y, xr[rg][ks][0].z, xr[rg][ks][0].w,
                          xr[rg][ks][1].x, xr[rg][ks][1].y, xr[rg][ks][1].z, xr[rg][ks][1].w};
#pragma unroll
            for (int j = 0; j < 8; j++) {
                unsigned short hj = f2bf(v[j]);
                ah[rg][j] = (short)hj;
                al[rg][j] = (short)f2bf(v[j] - bf2f(hj));
            }
        }
#pragma unroll
        for (int tt = 0; tt < 8; tt++) {
            const int o = tt * 16 + lr;
            const int eoff = o * D + ((((ks << 2) + lg) ^ (lr & 7)) << 3);
            short8 bh = *(const short8*)&sbuf[eoff];
            short8 bl = *(const short8*)&sbuf[16384 + eoff];
#pragma unroll
            for (int rg = 0; rg < 2; rg++) {
                acc[rg][tt] = __builtin_amdgcn_mfma_f32_16x16x32_bf16(ah[rg], bh, acc[rg][tt], 0, 0, 0);
                acc[rg][tt] = __builtin_amdgcn_mfma_f32_16x16x32_bf16(al[rg], bh, acc[rg][tt], 0, 0, 0);
                acc[rg][tt] = __builtin_amdgcn_mfma_f32_16x16x32_bf16(ah[rg], bl, acc[rg][tt], 0, 0, 0);
            }
        }
    }

    // C-writeout: scatter to LDS tile (rows padded to OW=136 ushorts), then
    // fully-coalesced short8 stores. C/D layout: col=lane&15, row=(lane>>4)*4+i.
    __syncthreads();   // all waves done reading W from sbuf
#pragma unroll
    for (int rg = 0; rg < 2; rg++)
#pragma unroll
        for (int i2 = 0; i2 < 4; i2++) {
            const int row = wv * 32 + rg * 16 + lg * 4 + i2;
#pragma unroll
            for (int tt = 0; tt < 8; tt++)
                sbuf[row * OW + tt * 16 + lr] = f2bf(acc[rg][tt][i2]);
        }
    __syncthreads();
#pragma unroll
    for (int it = 0; it < 8; it++) {
        const int idx = t + it * 256;       // 0..2047
        const int row = idx >> 4;
        const int seg = idx & 15;
        const int grow = blockIdx.x * 128 + row;
        if (grow < N)
            *(short8*)(h + (size_t)grow * D + seg * 8) =
                *(const short8*)&sbuf[row * OW + seg * 8];
    }
}

// ---------------------------------------------------------------------------
// Kernel 2: coarse bin into 196 partitions, LDS-staged LINE-LOCAL flushes.
// (unchanged control) entry = src | (dst & 511) << 17.
// ---------------------------------------------------------------------------
__global__ __launch_bounds__(256) void k_bin1(const int* __restrict__ src,
                                              const int* __restrict__ dst,
                                              int* __restrict__ gcur,
                                              unsigned* __restrict__ packed,
                                              int E, int np, int epb) {
    __shared__ unsigned stage[NP_MAX * SDEPTH];  // 49 KB
    __shared__ int scnt[NP_MAX];

    const int t = threadIdx.x;
    for (int i = t; i < np; i += 256) scnt[i] = 0;
    __syncthreads();

    const int beg = blockIdx.x * epb;
    const int end = min(beg + epb, E);
    for (int e = beg + t; e < end; e += 256) {
        const int d = dst[e];
        const int s = src[e];
        const int p = d >> PSHIFT;
        const unsigned entry = (unsigned)s | ((unsigned)(d & ((1 << PSHIFT) - 1)) << 17);
        const int slot = atomicAdd(&scnt[p], 1);
        if (slot < SDEPTH) {
            stage[p * SDEPTH + slot] = entry;
        } else {
            const int pos = atomicAdd(&gcur[p << 4], 1);
            if (pos - p * PCAP < PCAP) packed[pos] = entry;
        }
    }
    __syncthreads();

    for (int i = t; i < np; i += 256) {
        const int c = min(scnt[i], SDEPTH);
        if (c) {
            const int base = atomicAdd(&gcur[i << 4], c);
            const int lim = (i + 1) * PCAP;
            for (int j = 0; j < c; j++) {
                const int pos = base + j;
                if (pos < lim) packed[pos] = stage[i * SDEPTH + j];
            }
        }
    }
}

// ---------------------------------------------------------------------------
// Kernel 3: split each partition slab into its 8 bucket slabs.
// (unchanged control) 4 blocks/partition, chunked LDS counting-sort, 8 keys.
// ---------------------------------------------------------------------------
__global__ __launch_bounds__(256) void k_bin2(const unsigned* __restrict__ packed,
                                              const int* __restrict__ gcur,
                                              int* __restrict__ bcur,
                                              unsigned* __restrict__ bslab,
                                              int np) {
    __shared__ unsigned raw[CHUNK];   // 8 KB
    __shared__ unsigned srt[CHUNK];   // 8 KB
    __shared__ int c8[8], o8[9], cur8[8], gbase[8];

    const int p = blockIdx.x >> 2;
    const int qb = blockIdx.x & 3;
    const int t = threadIdx.x;

    const int base = p * PCAP;
    const int sz = min(gcur[p << 4] - base, PCAP);
    const int per = (sz + 3) >> 2;
    const int rbeg = qb * per;
    const int rend = min(rbeg + per, sz);
    const unsigned* pk = packed + (size_t)base;

    for (int cbeg = rbeg; cbeg < rend; cbeg += CHUNK) {
        const int n = min(CHUNK, rend - cbeg);
        for (int i = t; i < n; i += 256) raw[i] = pk[cbeg + i];
        if (t < 8) c8[t] = 0;
        __syncthreads();
        for (int i = t; i < n; i += 256) atomicAdd(&c8[raw[i] >> 23], 1);
        __syncthreads();
        if (t == 0) {
            int s = 0;
#pragma unroll
            for (int j = 0; j < 8; j++) { o8[j] = s; s += c8[j]; }
            o8[8] = s;
        }
        __syncthreads();
        if (t < 8) {
            cur8[t] = o8[t];
            gbase[t] = atomicAdd(&bcur[(p * 8 + t) << 4], c8[t]);
        }
        __syncthreads();
        for (int i = t; i < n; i += 256) {
            const unsigned e = raw[i];
            const int pos = atomicAdd(&cur8[e >> 23], 1);
            srt[pos] = e & 0x7FFFFFu;
        }
        __syncthreads();
#pragma unroll
        for (int b = 0; b < 8; b++) {
            const int cnt = o8[b + 1] - o8[b];
            const int gb = gbase[b];
            const int lim = (p * 8 + b + 1) * BCAP;
            const int m2 = min(cnt, max(0, lim - gb));
            for (int i = t; i < m2; i += 256) bslab[gb + i] = srt[o8[b] + i];
        }
        __syncthreads();
    }
}

// ---------------------------------------------------------------------------
// Kernel 4: gather (unchanged control). One block per 64-node bucket;
// 256-key LDS counting-sort; 4 src-phases (~8MB h window).
// ---------------------------------------------------------------------------
__global__ __launch_bounds__(256) void k_gather(const unsigned short* __restrict__ h,
                                                const unsigned* __restrict__ bslab,
                                                const int* __restrict__ bcur,
                                                float* __restrict__ out, int N) {
    __shared__ unsigned lsrc[BCAP];   // 10 KB
    __shared__ int cnt[256];
    __shared__ int off[257];
    __shared__ int curs[256];

    const int bk = blockIdx.x;
    const int t = threadIdx.x;
    const int hw = t >> 5;
    const int f = (t & 31) << 2;

    const int sz = min(bcur[bk << 4] - bk * BCAP, BCAP);
    const unsigned* pk = bslab + (size_t)bk * BCAP;

    cnt[t] = 0;
    __syncthreads();
    for (int i = t; i < sz; i += 256)
        atomicAdd(&cnt[(pk[i] >> 15) & 255u], 1);
    __syncthreads();
    if (t == 0) {
        int s = 0;
        for (int j = 0; j < 256; j++) { off[j] = s; s += cnt[j]; }
        off[256] = s;
    }
    __syncthreads();
    curs[t] = off[t];
    __syncthreads();
    for (int i = t; i < sz; i += 256) {
        unsigned p = pk[i];
        int pos = atomicAdd(&curs[(p >> 15) & 255u], 1);
        lsrc[pos] = p & 0x1FFFFu;
    }
    __syncthreads();

    float4 acc[8];
#pragma unroll
    for (int r = 0; r < 8; r++) acc[r] = make_float4(0.f, 0.f, 0.f, 0.f);

    for (int q = 0; q < 4; q++) {
#pragma unroll
        for (int r = 0; r < 8; r++) {
            const int nl = hw + (r << 3);
            const int idx = (nl << 2) + q;
            int j = off[idx];
            const int je = off[idx + 1];
            float4 a = acc[r];
            for (; j + 3 < je; j += 4) {
                int s0 = lsrc[j], s1 = lsrc[j + 1], s2 = lsrc[j + 2], s3 = lsrc[j + 3];
                ushort4 v0 = *(const ushort4*)(h + (size_t)s0 * D + f);
                ushort4 v1 = *(const ushort4*)(h + (size_t)s1 * D + f);
                ushort4 v2 = *(const ushort4*)(h + (size_t)s2 * D + f);
                ushort4 v3 = *(const ushort4*)(h + (size_t)s3 * D + f);
                a.x += bf2f(v0.x) + bf2f(v1.x) + bf2f(v2.x) + bf2f(v3.x);
                a.y += bf2f(v0.y) + bf2f(v1.y) + bf2f(v2.y) + bf2f(v3.y);
                a.z += bf2f(v0.z) + bf2f(v1.z) + bf2f(v2.z) + bf2f(v3.z);
                a.w += bf2f(v0.w) + bf2f(v1.w) + bf2f(v2.w) + bf2f(v3.w);
            }
            for (; j < je; j++) {
                int s0 = lsrc[j];
                ushort4 v0 = *(const ushort4*)(h + (size_t)s0 * D + f);
                a.x += bf2f(v0.x); a.y += bf2f(v0.y);
                a.z += bf2f(v0.z); a.w += bf2f(v0.w);
            }
            acc[r] = a;
        }
    }

#pragma unroll
    for (int r = 0; r < 8; r++) {
        int node = (bk << 6) + hw + (r << 3);
        if (node < N) *(float4*)(out + (size_t)node * D + f) = acc[r];
    }
}

extern "C" void kernel_launch(void* const* d_in, const int* in_sizes, int n_in,
                              void* d_out, int out_size, void* d_ws, size_t ws_size,
                              hipStream_t stream) {
    const float* x = (const float*)d_in[0];   // [N, 128]
    const float* W = (const float*)d_in[1];   // [128, 128]
    const int* ei  = (const int*)d_in[2];     // [2, E] flat
    float* out = (float*)d_out;               // [N, 128]

    const int N = in_sizes[0] / D;            // 100000
    const int E = in_sizes[2] / 2;            // 3200000
    const int np = (N + 511) >> PSHIFT;       // 196 partitions
    const int nb = (N + 63) >> 6;             // 1563 buckets
    const int epb = (E + NBF - 1) / NBF;      // 4167 edges per bin1 block

    const int* srcp = ei;
    const int* dstp = ei + E;

    // workspace layout (16B-aligned slabs)
    char* ws = (char*)d_ws;
    unsigned short* h = (unsigned short*)ws;
                                      ws += (size_t)N * D * 2;                // 25.6 MB
    unsigned* packed = (unsigned*)ws; ws += (size_t)np * PCAP * 4;            // 13.9 MB
    unsigned* bslab = (unsigned*)ws;  ws += (size_t)nb * BCAP * 4;            // 16.0 MB
    unsigned short* whl = (unsigned short*)ws;
                                      ws += (size_t)2 * 16384 * 2;            // 64 KB
    int* gcur = (int*)ws;             ws += (size_t)np * 64;                  // 12.5 KB
    int* bcur = (int*)ws;             ws += (size_t)nb * 64;                  // 100 KB

    k_init<<<(nb + 255) / 256, 256, 0, stream>>>(gcur, np, bcur, nb);
    k_prep<<<8, 256, 0, stream>>>(W, whl);
    k_gemm_mfma<<<(N + 127) / 128, 256, 0, stream>>>(x, whl, h, N);
    k_bin1<<<NBF, 256, 0, stream>>>(srcp, dstp, gcur, packed, E, np, epb);
    k_bin2<<<np * 4, 256, 0, stream>>>(packed, gcur, bcur, bslab, np);
    k_gather<<<nb, 256, 0, stream>>>(h, bslab, bcur, out, N);
}

// Round 8
// 272.128 us; speedup vs baseline: 1.3687x; 1.0037x over previous
//
#include <hip/hip_runtime.h>

#define D 128
#define PSHIFT 9                 // 512 nodes per partition
#define PCAP 17664               // partition slab cap (mean 16327, sigma~128, +10s)
#define SDEPTH 48                // bin1 LDS staging depth per partition
#define NP_MAX 256               // max partitions (static LDS sizing)
#define NBF 768                  // bin1 blocks (3 blocks/CU)
#define BCAP 2560                // per-bucket slab cap (mean 2048, sigma~45)
#define CHUNK 2048               // bin2 chunk size
#define OW 136                   // gemm writeout LDS row stride (ushorts)

typedef __attribute__((ext_vector_type(8))) short short8;
typedef __attribute__((ext_vector_type(4))) float f32x4;

__device__ __forceinline__ unsigned short f2bf(float f) {
    union { float f; unsigned int u; } c; c.f = f;
    unsigned int b = c.u;
    unsigned int r = (b + 0x7FFFu + ((b >> 16) & 1u)) >> 16;  // RTN-even
    return (unsigned short)r;
}
__device__ __forceinline__ float bf2f(unsigned short s) {
    union { unsigned int u; float f; } c; c.u = ((unsigned int)s) << 16;
    return c.f;
}

// ---------------------------------------------------------------------------
// Kernel 0 (merged init+prep): cursors + W -> swizzled hi/lo bf16 (once).
// ---------------------------------------------------------------------------
__global__ __launch_bounds__(256) void k_setup(const float* __restrict__ W,
                                               unsigned short* __restrict__ whl,
                                               int* __restrict__ gcur, int np,
                                               int* __restrict__ bcur, int nb) {
    const int i = blockIdx.x * 256 + threadIdx.x;   // 0..2047
    if (i < np) gcur[i << 4] = i * PCAP;
    if (i < nb) bcur[i << 4] = i * BCAP;
    if (i < (D * D / 8)) {
        const int o = i >> 4;
        const int gk = i & 15;
        const float* wp = W + o * D + gk * 8;
        float4 a0 = *(const float4*)wp;
        float4 a1 = *(const float4*)(wp + 4);
        float v[8] = {a0.x, a0.y, a0.z, a0.w, a1.x, a1.y, a1.z, a1.w};
        unsigned short hi[8], lo[8];
#pragma unroll
        for (int j = 0; j < 8; j++) {
            hi[j] = f2bf(v[j]);
            lo[j] = f2bf(v[j] - bf2f(hi[j]));
        }
        const int base = o * D + ((gk ^ (o & 7)) << 3);
        ushort4 h0 = {hi[0], hi[1], hi[2], hi[3]};
        ushort4 h1 = {hi[4], hi[5], hi[6], hi[7]};
        ushort4 l0 = {lo[0], lo[1], lo[2], lo[3]};
        ushort4 l1 = {lo[4], lo[5], lo[6], lo[7]};
        *(ushort4*)&whl[base] = h0;
        *(ushort4*)&whl[base + 4] = h1;
        *(ushort4*)&whl[16384 + base] = l0;
        *(ushort4*)&whl[16384 + base + 4] = l1;
    }
}

// ---------------------------------------------------------------------------
// Kernel 1: h = bf16(x @ W^T) via MFMA, bf16 hi/lo split. (unchanged control)
// ---------------------------------------------------------------------------
__global__ __launch_bounds__(256, 2) void k_gemm_mfma(const float* __restrict__ x,
                                                      const unsigned short* __restrict__ whl,
                                                      unsigned short* __restrict__ h,
                                                      int N) {
    __shared__ unsigned short sbuf[2 * 16384];   // 64 KB: WhWl; later writeout tile

    const int t = threadIdx.x;

    {
        const float4* g4 = (const float4*)whl;
        float4* l4 = (float4*)sbuf;
#pragma unroll
        for (int i = 0; i < 16; i++) l4[t + i * 256] = g4[t + i * 256];
    }
    __syncthreads();

    const int lane = t & 63;
    const int wv = t >> 6;      // 0..3
    const int lr = lane & 15;
    const int lg = lane >> 4;
    const int rowbase = blockIdx.x * 128 + wv * 32;

    float4 xr[2][4][2];
#pragma unroll
    for (int rg = 0; rg < 2; rg++) {
        const int row = rowbase + rg * 16 + lr;
        const float* xp = x + (size_t)row * D + lg * 8;
        const bool ok = (row < N);
#pragma unroll
        for (int ks = 0; ks < 4; ks++) {
            xr[rg][ks][0] = ok ? *(const float4*)(xp + ks * 32) : make_float4(0.f, 0.f, 0.f, 0.f);
            xr[rg][ks][1] = ok ? *(const float4*)(xp + ks * 32 + 4) : make_float4(0.f, 0.f, 0.f, 0.f);
        }
    }

    f32x4 acc[2][8];
#pragma unroll
    for (int a = 0; a < 2; a++)
#pragma unroll
        for (int b = 0; b < 8; b++)
            acc[a][b] = (f32x4){0.f, 0.f, 0.f, 0.f};

#pragma unroll
    for (int ks = 0; ks < 4; ks++) {
        short8 ah[2], al[2];
#pragma unroll
        for (int rg = 0; rg < 2; rg++) {
            float v[8] = {xr[rg][ks][0].x, xr[rg][ks][0].y, xr[rg][ks][0].z, xr[rg][ks][0].w,
                          xr[rg][ks][1].x, xr[rg][ks][1].y, xr[rg][ks][1].z, xr[rg][ks][1].w};
#pragma unroll
            for (int j = 0; j < 8; j++) {
                unsigned short hj = f2bf(v[j]);
                ah[rg][j] = (short)hj;
                al[rg][j] = (short)f2bf(v[j] - bf2f(hj));
            }
        }
#pragma unroll
        for (int tt = 0; tt < 8; tt++) {
            const int o = tt * 16 + lr;
            const int eoff = o * D + ((((ks << 2) + lg) ^ (lr & 7)) << 3);
            short8 bh = *(const short8*)&sbuf[eoff];
            short8 bl = *(const short8*)&sbuf[16384 + eoff];
#pragma unroll
            for (int rg = 0; rg < 2; rg++) {
                acc[rg][tt] = __builtin_amdgcn_mfma_f32_16x16x32_bf16(ah[rg], bh, acc[rg][tt], 0, 0, 0);
                acc[rg][tt] = __builtin_amdgcn_mfma_f32_16x16x32_bf16(al[rg], bh, acc[rg][tt], 0, 0, 0);
                acc[rg][tt] = __builtin_amdgcn_mfma_f32_16x16x32_bf16(ah[rg], bl, acc[rg][tt], 0, 0, 0);
            }
        }
    }

    __syncthreads();
#pragma unroll
    for (int rg = 0; rg < 2; rg++)
#pragma unroll
        for (int i2 = 0; i2 < 4; i2++) {
            const int row = wv * 32 + rg * 16 + lg * 4 + i2;
#pragma unroll
            for (int tt = 0; tt < 8; tt++)
                sbuf[row * OW + tt * 16 + lr] = f2bf(acc[rg][tt][i2]);
        }
    __syncthreads();
#pragma unroll
    for (int it = 0; it < 8; it++) {
        const int idx = t + it * 256;
        const int row = idx >> 4;
        const int seg = idx & 15;
        const int grow = blockIdx.x * 128 + row;
        if (grow < N)
            *(short8*)(h + (size_t)grow * D + seg * 8) =
                *(const short8*)&sbuf[row * OW + seg * 8];
    }
}

// ---------------------------------------------------------------------------
// Kernel 2: coarse bin into 196 partitions, LDS-staged flushes. (control)
// ---------------------------------------------------------------------------
__global__ __launch_bounds__(256) void k_bin1(const int* __restrict__ src,
                                              const int* __restrict__ dst,
                                              int* __restrict__ gcur,
                                              unsigned* __restrict__ packed,
                                              int E, int np, int epb) {
    __shared__ unsigned stage[NP_MAX * SDEPTH];  // 49 KB
    __shared__ int scnt[NP_MAX];

    const int t = threadIdx.x;
    for (int i = t; i < np; i += 256) scnt[i] = 0;
    __syncthreads();

    const int beg = blockIdx.x * epb;
    const int end = min(beg + epb, E);
    for (int e = beg + t; e < end; e += 256) {
        const int d = dst[e];
        const int s = src[e];
        const int p = d >> PSHIFT;
        const unsigned entry = (unsigned)s | ((unsigned)(d & ((1 << PSHIFT) - 1)) << 17);
        const int slot = atomicAdd(&scnt[p], 1);
        if (slot < SDEPTH) {
            stage[p * SDEPTH + slot] = entry;
        } else {
            const int pos = atomicAdd(&gcur[p << 4], 1);
            if (pos - p * PCAP < PCAP) packed[pos] = entry;
        }
    }
    __syncthreads();

    for (int i = t; i < np; i += 256) {
        const int c = min(scnt[i], SDEPTH);
        if (c) {
            const int base = atomicAdd(&gcur[i << 4], c);
            const int lim = (i + 1) * PCAP;
            for (int j = 0; j < c; j++) {
                const int pos = base + j;
                if (pos < lim) packed[pos] = stage[i * SDEPTH + j];
            }
        }
    }
}

// ---------------------------------------------------------------------------
// Kernel 3: partition slab -> 8 bucket slabs, chunked 8-key sort. (control)
// ---------------------------------------------------------------------------
__global__ __launch_bounds__(256) void k_bin2(const unsigned* __restrict__ packed,
                                              const int* __restrict__ gcur,
                                              int* __restrict__ bcur,
                                              unsigned* __restrict__ bslab,
                                              int np) {
    __shared__ unsigned raw[CHUNK];   // 8 KB
    __shared__ unsigned srt[CHUNK];   // 8 KB
    __shared__ int c8[8], o8[9], cur8[8], gbase[8];

    const int p = blockIdx.x >> 2;
    const int qb = blockIdx.x & 3;
    const int t = threadIdx.x;

    const int base = p * PCAP;
    const int sz = min(gcur[p << 4] - base, PCAP);
    const int per = (sz + 3) >> 2;
    const int rbeg = qb * per;
    const int rend = min(rbeg + per, sz);
    const unsigned* pk = packed + (size_t)base;

    for (int cbeg = rbeg; cbeg < rend; cbeg += CHUNK) {
        const int n = min(CHUNK, rend - cbeg);
        for (int i = t; i < n; i += 256) raw[i] = pk[cbeg + i];
        if (t < 8) c8[t] = 0;
        __syncthreads();
        for (int i = t; i < n; i += 256) atomicAdd(&c8[raw[i] >> 23], 1);
        __syncthreads();
        if (t == 0) {
            int s = 0;
#pragma unroll
            for (int j = 0; j < 8; j++) { o8[j] = s; s += c8[j]; }
            o8[8] = s;
        }
        __syncthreads();
        if (t < 8) {
            cur8[t] = o8[t];
            gbase[t] = atomicAdd(&bcur[(p * 8 + t) << 4], c8[t]);
        }
        __syncthreads();
        for (int i = t; i < n; i += 256) {
            const unsigned e = raw[i];
            const int pos = atomicAdd(&cur8[e >> 23], 1);
            srt[pos] = e & 0x7FFFFFu;
        }
        __syncthreads();
#pragma unroll
        for (int b = 0; b < 8; b++) {
            const int cnt = o8[b + 1] - o8[b];
            const int gb = gbase[b];
            const int lim = (p * 8 + b + 1) * BCAP;
            const int m2 = min(cnt, max(0, lim - gb));
            for (int i = t; i < m2; i += 256) bslab[gb + i] = srt[o8[b] + i];
        }
        __syncthreads();
    }
}

// ---------------------------------------------------------------------------
// Kernel 4: gather — 512 threads (8 waves). Round-7 code, now launched with
// the MATCHING block size (r7 failure: kernel assumed 512, launch passed 256
// -> half the nodes never written, sort offsets corrupted).
// ---------------------------------------------------------------------------
__global__ __launch_bounds__(512) void k_gather(const unsigned short* __restrict__ h,
                                                const unsigned* __restrict__ bslab,
                                                const int* __restrict__ bcur,
                                                float* __restrict__ out, int N) {
    __shared__ unsigned lsrc[BCAP];   // 10 KB
    __shared__ int cnt[256];
    __shared__ int off[257];
    __shared__ int curs[256];
    __shared__ int wpart[4];

    const int bk = blockIdx.x;
    const int t = threadIdx.x;
    const int hw = t >> 5;            // half-wave 0..15
    const int f = (t & 31) << 2;      // feature offset

    const int sz = min(bcur[bk << 4] - bk * BCAP, BCAP);
    const unsigned* pk = bslab + (size_t)bk * BCAP;

    if (t < 256) cnt[t] = 0;
    __syncthreads();
    for (int i = t; i < sz; i += 512)
        atomicAdd(&cnt[(pk[i] >> 15) & 255u], 1);
    __syncthreads();

    // parallel exclusive scan of cnt[256]: waves 0..3 shfl-scan + 4 partials
    const int lane = t & 63;
    const int w = t >> 6;
    int c = 0, v = 0;
    if (t < 256) {
        c = cnt[t];
        v = c;
#pragma unroll
        for (int d2 = 1; d2 < 64; d2 <<= 1) {
            int up = __shfl_up(v, d2, 64);
            if (lane >= d2) v += up;
        }
        if (lane == 63) wpart[w] = v;
    }
    __syncthreads();
    if (t == 0) {
        int s = 0;
#pragma unroll
        for (int j2 = 0; j2 < 4; j2++) { const int x2 = wpart[j2]; wpart[j2] = s; s += x2; }
        off[256] = s;
    }
    __syncthreads();
    if (t < 256) {
        const int e = v - c + wpart[w];
        off[t] = e;
        curs[t] = e;
    }
    __syncthreads();

    for (int i = t; i < sz; i += 512) {
        unsigned p = pk[i];
        int pos = atomicAdd(&curs[(p >> 15) & 255u], 1);
        lsrc[pos] = p & 0x1FFFFu;
    }
    __syncthreads();

    float4 acc[4];
#pragma unroll
    for (int r = 0; r < 4; r++) acc[r] = make_float4(0.f, 0.f, 0.f, 0.f);

    for (int q = 0; q < 4; q++) {        // src-quadrant phase (L2 window)
#pragma unroll
        for (int r = 0; r < 4; r++) {
            const int nl = hw + (r << 4);
            const int idx = (nl << 2) + q;
            int j = off[idx];
            const int je = off[idx + 1];
            float4 a = acc[r];
            for (; j + 3 < je; j += 4) {
                int s0 = lsrc[j], s1 = lsrc[j + 1], s2 = lsrc[j + 2], s3 = lsrc[j + 3];
                ushort4 v0 = *(const ushort4*)(h + (size_t)s0 * D + f);
                ushort4 v1 = *(const ushort4*)(h + (size_t)s1 * D + f);
                ushort4 v2 = *(const ushort4*)(h + (size_t)s2 * D + f);
                ushort4 v3 = *(const ushort4*)(h + (size_t)s3 * D + f);
                a.x += bf2f(v0.x) + bf2f(v1.x) + bf2f(v2.x) + bf2f(v3.x);
                a.y += bf2f(v0.y) + bf2f(v1.y) + bf2f(v2.y) + bf2f(v3.y);
                a.z += bf2f(v0.z) + bf2f(v1.z) + bf2f(v2.z) + bf2f(v3.z);
                a.w += bf2f(v0.w) + bf2f(v1.w) + bf2f(v2.w) + bf2f(v3.w);
            }
            for (; j < je; j++) {
                int s0 = lsrc[j];
                ushort4 v0 = *(const ushort4*)(h + (size_t)s0 * D + f);
                a.x += bf2f(v0.x); a.y += bf2f(v0.y);
                a.z += bf2f(v0.z); a.w += bf2f(v0.w);
            }
            acc[r] = a;
        }
    }

#pragma unroll
    for (int r = 0; r < 4; r++) {
        const int node = (bk << 6) + hw + (r << 4);
        if (node < N) *(float4*)(out + (size_t)node * D + f) = acc[r];
    }
}

extern "C" void kernel_launch(void* const* d_in, const int* in_sizes, int n_in,
                              void* d_out, int out_size, void* d_ws, size_t ws_size,
                              hipStream_t stream) {
    const float* x = (const float*)d_in[0];   // [N, 128]
    const float* W = (const float*)d_in[1];   // [128, 128]
    const int* ei  = (const int*)d_in[2];     // [2, E] flat
    float* out = (float*)d_out;               // [N, 128]

    const int N = in_sizes[0] / D;            // 100000
    const int E = in_sizes[2] / 2;            // 3200000
    const int np = (N + 511) >> PSHIFT;       // 196 partitions
    const int nb = (N + 63) >> 6;             // 1563 buckets
    const int epb = (E + NBF - 1) / NBF;      // 4167 edges per bin1 block

    const int* srcp = ei;
    const int* dstp = ei + E;

    // workspace layout (16B-aligned slabs)
    char* ws = (char*)d_ws;
    unsigned short* h = (unsigned short*)ws;
                                      ws += (size_t)N * D * 2;                // 25.6 MB
    unsigned* packed = (unsigned*)ws; ws += (size_t)np * PCAP * 4;            // 13.9 MB
    unsigned* bslab = (unsigned*)ws;  ws += (size_t)nb * BCAP * 4;            // 16.0 MB
    unsigned short* whl = (unsigned short*)ws;
                                      ws += (size_t)2 * 16384 * 2;            // 64 KB
    int* gcur = (int*)ws;             ws += (size_t)np * 64;                  // 12.5 KB
    int* bcur = (int*)ws;             ws += (size_t)nb * 64;                  // 100 KB

    k_setup<<<8, 256, 0, stream>>>(W, whl, gcur, np, bcur, nb);
    k_gemm_mfma<<<(N + 127) / 128, 256, 0, stream>>>(x, whl, h, N);
    k_bin1<<<NBF, 256, 0, stream>>>(srcp, dstp, gcur, packed, E, np, epb);
    k_bin2<<<np * 4, 256, 0, stream>>>(packed, gcur, bcur, bslab, np);
    k_gather<<<nb, 512, 0, stream>>>(h, bslab, bcur, out, N);
}